// Round 3
// baseline (1907.574 us; speedup 1.0000x reference)
//
#include <hip/hip_runtime.h>
#include <math.h>

typedef unsigned short u16;
typedef unsigned int   u32;

#define B    128
#define H    1024
#define SEQ  512
#define VOUT 32000

__device__ __forceinline__ float b2f(u32 u){ return __uint_as_float((u & 0xffffu) << 16); }
__device__ __forceinline__ float sigm(float x){ return 1.0f / (1.0f + expf(-x)); }

// generic element load: bf=1 -> data is bf16 (u16); bf=0 -> data is f32
__device__ __forceinline__ float ldf(const void* p, size_t i, int bf){
  return bf ? b2f(((const u16*)p)[i]) : ((const float*)p)[i];
}

// ---- runtime input-dtype detection (1 = bf16, 0 = f32) ----
// Proven across R1/R2: selects f32 for this harness; kept as insurance.
__global__ void k_detect(const u16* __restrict__ enc, int* __restrict__ flag){
  __shared__ int cnt;
  if (threadIdx.x == 0) cnt = 0;
  __syncthreads();
  int c = 0;
  for (int j = threadIdx.x; j < 512; j += 256){
    u32 u = enc[j];
    u32 e = (u >> 7) & 0xFFu;
    c += (u == 0u || (e >= 100u && e <= 130u)) ? 1 : 0;
  }
  atomicAdd(&cnt, c);
  __syncthreads();
  if (threadIdx.x == 0) *flag = (cnt > 410) ? 1 : 0;
}

// ---- init: X = emb[idx] (f32), Hb = h1 (f32) ----
__global__ void k_init(const int* __restrict__ idx, const void* __restrict__ emb,
                       const void* __restrict__ h1, float* __restrict__ X, float* __restrict__ Hb,
                       const int* __restrict__ flagp){
  int bf = *flagp;
  int t = blockIdx.x * 256 + threadIdx.x;   // B*H threads
  int b = t >> 10, h = t & (H - 1);
  X[t]  = ldf(emb, (size_t)idx[b] * H + h, bf);
  Hb[t] = ldf(h1, t, bf);
}

// ---- generic C[B,N] = A(f32,[B,K]) @ W([N,K])^T, tiled; W/bias offsets in elements ----
// MODE 0: C = acc + bias (+bias2)
// MODE 1: C += acc
// MODE 2: C = C * 2*sigmoid(acc + bias)      (mogrifier step, in-place gate-mult)
// MODE 3: C = tanh(acc + bias)               (concat)
template<int MODE>
__global__ __launch_bounds__(256)
void gemm_bt(const float* __restrict__ A, const void* __restrict__ W, size_t wOff,
             const void* __restrict__ bias, size_t bOff, const void* __restrict__ bias2,
             float* __restrict__ C, int K, int N,
             const int* __restrict__ flagp)
{
  const int bf = *flagp;
  __shared__ float As[32][132];   // [k][b], padded
  __shared__ float Ws[64][33];    // [n][k], padded
  const int t  = threadIdx.x;
  const int n0 = blockIdx.x * 64;
  const int sb = t >> 1,  sk = (t & 1) << 4;   // A staging: b, k-offset
  const int wn = t >> 2,  wk = (t & 3) << 3;   // W staging: n, k-offset
  const int bx = (t & 15) << 3;                // 8 b-rows per thread
  const int ny = (t >> 4) << 2;                // 4 n-cols per thread

  float acc[8][4];
  #pragma unroll
  for (int i = 0; i < 8; ++i)
    #pragma unroll
    for (int j = 0; j < 4; ++j) acc[i][j] = 0.f;

  for (int k0 = 0; k0 < K; k0 += 32){
    const float4* Ap = (const float4*)(A + (size_t)sb * K + k0 + sk);
    float4 a0 = Ap[0], a1 = Ap[1], a2 = Ap[2], a3 = Ap[3];
    size_t we = wOff + (size_t)(n0 + wn) * K + k0 + wk;
    float w0,w1,w2,w3,w4,w5,w6,w7;
    if (bf){
      uint4 wv = *(const uint4*)((const u16*)W + we);
      w0=b2f(wv.x); w1=b2f(wv.x>>16); w2=b2f(wv.y); w3=b2f(wv.y>>16);
      w4=b2f(wv.z); w5=b2f(wv.z>>16); w6=b2f(wv.w); w7=b2f(wv.w>>16);
    } else {
      const float* Wf = (const float*)W + we;
      float4 p = *(const float4*)Wf, q = *(const float4*)(Wf + 4);
      w0=p.x; w1=p.y; w2=p.z; w3=p.w; w4=q.x; w5=q.y; w6=q.z; w7=q.w;
    }

    As[sk+ 0][sb]=a0.x; As[sk+ 1][sb]=a0.y; As[sk+ 2][sb]=a0.z; As[sk+ 3][sb]=a0.w;
    As[sk+ 4][sb]=a1.x; As[sk+ 5][sb]=a1.y; As[sk+ 6][sb]=a1.z; As[sk+ 7][sb]=a1.w;
    As[sk+ 8][sb]=a2.x; As[sk+ 9][sb]=a2.y; As[sk+10][sb]=a2.z; As[sk+11][sb]=a2.w;
    As[sk+12][sb]=a3.x; As[sk+13][sb]=a3.y; As[sk+14][sb]=a3.z; As[sk+15][sb]=a3.w;
    Ws[wn][wk+0]=w0; Ws[wn][wk+1]=w1; Ws[wn][wk+2]=w2; Ws[wn][wk+3]=w3;
    Ws[wn][wk+4]=w4; Ws[wn][wk+5]=w5; Ws[wn][wk+6]=w6; Ws[wn][wk+7]=w7;
    __syncthreads();

    #pragma unroll
    for (int kk = 0; kk < 32; ++kk){
      float a[8], w[4];
      #pragma unroll
      for (int i = 0; i < 8; ++i) a[i] = As[kk][bx+i];
      #pragma unroll
      for (int j = 0; j < 4; ++j) w[j] = Ws[ny+j][kk];
      #pragma unroll
      for (int i = 0; i < 8; ++i)
        #pragma unroll
        for (int j = 0; j < 4; ++j) acc[i][j] = fmaf(a[i], w[j], acc[i][j]);
    }
    __syncthreads();
  }

  #pragma unroll
  for (int j = 0; j < 4; ++j){
    int n = n0 + ny + j;
    float bj = 0.f;
    if (bias)  bj += ldf(bias, bOff + n, bf);
    if (bias2) bj += ldf(bias2, n, bf);
    #pragma unroll
    for (int i = 0; i < 8; ++i){
      int b = bx + i;
      size_t o = (size_t)b * N + n;
      float v = acc[i][j] + bj;
      if (MODE == 0)      C[o] = v;
      else if (MODE == 1) C[o] += acc[i][j];
      else if (MODE == 2) C[o] = C[o] * 2.f * sigm(v);
      else                C[o] = tanhf(v);
    }
  }
}

// ---- LSTM pointwise: h = sigm(o)*tanh(sigm(f)*c + sigm(i)*tanh(g)) ----
__global__ void k_lstm_pw(const float* __restrict__ G, const void* __restrict__ cprev,
                          float* __restrict__ hout, float* __restrict__ hf,
                          const int* __restrict__ flagp){
  int bf = *flagp;
  int t = blockIdx.x * 256 + threadIdx.x;   // B*H
  int b = t >> 10, h = t & (H - 1);
  const float* g = G + (size_t)b * 4 * H;
  float iv = sigm(g[h]);
  float fv = sigm(g[H + h]);
  float gv = tanhf(g[2*H + h]);
  float ov = sigm(g[3*H + h]);
  float c = cprev ? fv * ldf(cprev, t, bf) : 0.f;
  c += iv * gv;
  float hv = ov * tanhf(c);
  hout[t] = hv;
  if (hf) hf[t] = hv;        // f32 hidden straight into d_out
}

// ---- layer-2 mogrifier collapse: X *= 8*sig(b0)*sig(b2)*sig(b4) ----
__global__ void k_scale2(float* __restrict__ X, const void* __restrict__ mb,
                         const int* __restrict__ flagp){
  int bf = *flagp;
  int t = blockIdx.x * 256 + threadIdx.x;   // B*H
  int h = t & (H - 1);
  float s = 8.f * sigm(ldf(mb, h, bf)) * sigm(ldf(mb, 2*H + h, bf)) * sigm(ldf(mb, 4*H + h, bf));
  X[t] *= s;
}

// ---- scores[b][s] = sum_h R[b][h]*enc[s][b][h]; one wave per (b,s) ----
__global__ __launch_bounds__(256)
void k_scores(const float* __restrict__ R, const void* __restrict__ enc, float* __restrict__ SC,
              const int* __restrict__ flagp){
  int bf = *flagp;
  int wid  = (blockIdx.x << 2) + (threadIdx.x >> 6);
  int lane = threadIdx.x & 63;
  int b = wid >> 9, s = wid & (SEQ - 1);
  size_t base = ((size_t)s * B + b) * H;
  const float* r = R + (size_t)b * H;
  float acc = 0.f;
  #pragma unroll
  for (int k0 = 0; k0 < H; k0 += 512){
    int h = k0 + lane * 8;
    float e0,e1,e2,e3,e4,e5,e6,e7;
    if (bf){
      uint4 u = *(const uint4*)((const u16*)enc + base + h);
      e0=b2f(u.x); e1=b2f(u.x>>16); e2=b2f(u.y); e3=b2f(u.y>>16);
      e4=b2f(u.z); e5=b2f(u.z>>16); e6=b2f(u.w); e7=b2f(u.w>>16);
    } else {
      const float* ef = (const float*)enc + base + h;
      float4 p = *(const float4*)ef, q = *(const float4*)(ef + 4);
      e0=p.x; e1=p.y; e2=p.z; e3=p.w; e4=q.x; e5=q.y; e6=q.z; e7=q.w;
    }
    float4 r0 = *(const float4*)(r + h);
    float4 r1 = *(const float4*)(r + h + 4);
    acc += e0*r0.x + e1*r0.y + e2*r0.z + e3*r0.w
         + e4*r1.x + e5*r1.y + e6*r1.z + e7*r1.w;
  }
  #pragma unroll
  for (int o = 32; o; o >>= 1) acc += __shfl_down(acc, o);
  if (lane == 0) SC[(size_t)b * SEQ + s] = acc;
}

// ---- softmax over S (in-place, f32), one block per b ----
__global__ __launch_bounds__(256)
void k_softmax_s(float* __restrict__ SC){
  int b = blockIdx.x, t = threadIdx.x;
  float* row = SC + (size_t)b * SEQ;
  float v0 = row[t], v1 = row[t + 256];
  __shared__ float rm[4], rs[4];
  int lane = t & 63, w = t >> 6;
  float m = fmaxf(v0, v1);
  #pragma unroll
  for (int o = 32; o; o >>= 1) m = fmaxf(m, __shfl_down(m, o));
  if (!lane) rm[w] = m;
  __syncthreads();
  float M = fmaxf(fmaxf(rm[0], rm[1]), fmaxf(rm[2], rm[3]));
  float e0 = expf(v0 - M), e1 = expf(v1 - M);
  float s = e0 + e1;
  #pragma unroll
  for (int o = 32; o; o >>= 1) s += __shfl_down(s, o);
  if (!lane) rs[w] = s;
  __syncthreads();
  float inv = 1.f / (rs[0] + rs[1] + rs[2] + rs[3]);
  row[t] = e0 * inv; row[t + 256] = e1 * inv;
}

// ---- context partials: CP[ch][b][h] = sum_{s in chunk} attn[b][s]*enc[s][b][h] ----
__global__ __launch_bounds__(256)
void k_context(const float* __restrict__ SC, const void* __restrict__ enc, float* __restrict__ CP,
               const int* __restrict__ flagp){
  int bf = *flagp;
  int b = blockIdx.x, ch = blockIdx.y, t = threadIdx.x;
  __shared__ float aw[128];
  if (t < 128) aw[t] = SC[(size_t)b * SEQ + ch * 128 + t];
  __syncthreads();
  int h0 = t << 2;
  float a0=0.f, a1=0.f, a2=0.f, a3=0.f;
  for (int ss = 0; ss < 128; ++ss){
    size_t off = ((size_t)(ch * 128 + ss) * B + b) * H + h0;
    float e0,e1,e2,e3;
    if (bf){
      uint2 u = *(const uint2*)((const u16*)enc + off);
      e0=b2f(u.x); e1=b2f(u.x>>16); e2=b2f(u.y); e3=b2f(u.y>>16);
    } else {
      float4 u = *(const float4*)((const float*)enc + off);
      e0=u.x; e1=u.y; e2=u.z; e3=u.w;
    }
    float wgt = aw[ss];
    a0 = fmaf(wgt, e0, a0);
    a1 = fmaf(wgt, e1, a1);
    a2 = fmaf(wgt, e2, a2);
    a3 = fmaf(wgt, e3, a3);
  }
  float4 o4 = {a0, a1, a2, a3};
  *(float4*)(CP + ((size_t)ch * B + b) * H + h0) = o4;
}

// ---- CAT[b][0:H]=R, CAT[b][H:2H]=sum of 4 context partials ----
__global__ void k_cat(const float* __restrict__ R, const float* __restrict__ CP, float* __restrict__ CAT){
  int t = blockIdx.x * 256 + threadIdx.x;  // B*2H
  int b = t >> 11, k = t & 2047;
  float v;
  if (k < H) v = R[(size_t)b * H + k];
  else {
    size_t o = (size_t)b * H + (k - H);
    v = CP[o] + CP[(size_t)B*H + o] + CP[2*(size_t)B*H + o] + CP[3*(size_t)B*H + o];
  }
  CAT[t] = v;
}

// ---- softmax over VOUT, f32 in-place in d_out, one block per b ----
__global__ __launch_bounds__(256)
void k_softmax_v(float* __restrict__ out){
  int b = blockIdx.x, t = threadIdx.x;
  float* row = out + (size_t)b * VOUT;
  __shared__ float rm[4], rs[4];
  int lane = t & 63, w = t >> 6;
  float m = -3.0e38f;
  for (int i = 4*t; i < VOUT; i += 1024){
    float4 v = *(const float4*)(row + i);
    m = fmaxf(m, fmaxf(fmaxf(v.x, v.y), fmaxf(v.z, v.w)));
  }
  #pragma unroll
  for (int o = 32; o; o >>= 1) m = fmaxf(m, __shfl_down(m, o));
  if (!lane) rm[w] = m;
  __syncthreads();
  float M = fmaxf(fmaxf(rm[0], rm[1]), fmaxf(rm[2], rm[3]));
  float s = 0.f;
  for (int i = 4*t; i < VOUT; i += 1024){
    float4 v = *(const float4*)(row + i);
    s += expf(v.x-M) + expf(v.y-M) + expf(v.z-M) + expf(v.w-M);
  }
  #pragma unroll
  for (int o = 32; o; o >>= 1) s += __shfl_down(s, o);
  if (!lane) rs[w] = s;
  __syncthreads();
  float inv = 1.f / (rs[0] + rs[1] + rs[2] + rs[3]);
  for (int i = 4*t; i < VOUT; i += 1024){
    float4 v = *(const float4*)(row + i);
    v.x = expf(v.x-M)*inv; v.y = expf(v.y-M)*inv;
    v.z = expf(v.z-M)*inv; v.w = expf(v.w-M)*inv;
    *(float4*)(row + i) = v;
  }
}

extern "C" void kernel_launch(void* const* d_in, const int* in_sizes, int n_in,
                              void* d_out, int out_size, void* d_ws, size_t ws_size,
                              hipStream_t stream){
  (void)in_sizes; (void)n_in; (void)out_size; (void)ws_size;
  const int* idx   = (const int*)d_in[0];
  const void* enc  = d_in[1];
  const void* h1   = d_in[2];
  const void* c1   = d_in[3];
  const void* emb  = d_in[4];
  const void* mog1W= d_in[5];
  const void* mog1b= d_in[6];
  const void* Wih1 = d_in[7];
  const void* Whh1 = d_in[8];
  const void* bih1 = d_in[9];
  const void* bhh1 = d_in[10];
  // d_in[11] mog2_W: dead (layer-2 mogrifier h stays 0)
  const void* mog2b= d_in[12];
  const void* Wih2 = d_in[13];
  // d_in[14] lstm2_Whh: dead (h=0)
  const void* bih2 = d_in[15];
  const void* bhh2 = d_in[16];
  const void* fcW  = d_in[17];
  const void* fcb  = d_in[18];
  const void* ccW  = d_in[19];
  const void* ccb  = d_in[20];
  const void* outW = d_in[21];
  const void* outb = d_in[22];

  float* X   = (float*)d_ws;        // B*H   (x / later concat_out)
  float* Hb  = X  + B*H;            // B*H   (h)
  float* G   = Hb + B*H;            // B*4H  (gates; later reused as context partials)
  float* H2  = G  + 4*B*H;          // B*H
  float* R   = H2 + B*H;            // B*H   (rnn_out)
  float* SC  = R  + B*H;            // B*SEQ (scores -> attn)
  float* CAT = SC + B*SEQ;          // B*2H
  int*  FLAG = (int*)(CAT + (size_t)B*2*H);
  float* CP  = G;                   // 4*B*H context partials (G dead by then)

  float* out_f = (float*)d_out;               // [B, VOUT] probs
  float* hid_f = out_f + (size_t)B * VOUT;    // [1, B, H] hidden (f32)

  k_detect<<<1, 256, 0, stream>>>((const u16*)enc, FLAG);
  k_init<<<B*H/256, 256, 0, stream>>>(idx, emb, h1, X, Hb, FLAG);
  // layer-1 mogrifier: i even -> x = 2sig(h@W^T+b)*x ; i odd -> h = 2sig(x@W^T+b)*h
  for (int i = 0; i < 5; ++i){
    const float* a = (i & 1) ? X : Hb;
    float*       c = (i & 1) ? Hb : X;
    gemm_bt<2><<<H/64, 256, 0, stream>>>(a, mog1W, (size_t)i*H*H, mog1b, (size_t)i*H,
                                         nullptr, c, H, H, FLAG);
  }
  gemm_bt<0><<<4*H/64, 256, 0, stream>>>(X,  Wih1, 0, bih1, 0, bhh1, G, H, 4*H, FLAG);
  gemm_bt<1><<<4*H/64, 256, 0, stream>>>(Hb, Whh1, 0, nullptr, 0, nullptr, G, H, 4*H, FLAG);
  k_lstm_pw<<<B*H/256, 256, 0, stream>>>(G, c1, X, nullptr, FLAG);   // h1n -> X (= layer-2 x)
  k_scale2<<<B*H/256, 256, 0, stream>>>(X, mog2b, FLAG);             // layer-2 mogrifier collapse
  gemm_bt<0><<<4*H/64, 256, 0, stream>>>(X, Wih2, 0, bih2, 0, bhh2, G, H, 4*H, FLAG);
  k_lstm_pw<<<B*H/256, 256, 0, stream>>>(G, nullptr, H2, hid_f, FLAG); // h2 -> H2 + f32 hidden out
  gemm_bt<0><<<H/64, 256, 0, stream>>>(H2, fcW, 0, fcb, 0, nullptr, R, H, H, FLAG);
  k_scores<<<B*SEQ/4, 256, 0, stream>>>(R, enc, SC, FLAG);
  k_softmax_s<<<B, 256, 0, stream>>>(SC);
  k_context<<<dim3(B, 4), 256, 0, stream>>>(SC, enc, CP, FLAG);
  k_cat<<<B*2*H/256, 256, 0, stream>>>(R, CP, CAT);
  gemm_bt<3><<<H/64, 256, 0, stream>>>(CAT, ccW, 0, ccb, 0, nullptr, X, 2*H, H, FLAG);
  gemm_bt<0><<<VOUT/64, 256, 0, stream>>>(X, outW, 0, outb, 0, nullptr, out_f, H, VOUT, FLAG);
  k_softmax_v<<<B, 256, 0, stream>>>(out_f);
}

// Round 4
// 1029.175 us; speedup vs baseline: 1.8535x; 1.8535x over previous
//
#include <hip/hip_runtime.h>
#include <math.h>

typedef unsigned short u16;
typedef unsigned int   u32;

#define B    128
#define H    1024
#define SEQ  512
#define VOUT 32000

__device__ __forceinline__ float b2f(u32 u){ return __uint_as_float((u & 0xffffu) << 16); }
__device__ __forceinline__ float sigm(float x){ return 1.0f / (1.0f + expf(-x)); }

// generic element load: bf=1 -> data is bf16 (u16); bf=0 -> data is f32
__device__ __forceinline__ float ldf(const void* p, size_t i, int bf){
  return bf ? b2f(((const u16*)p)[i]) : ((const float*)p)[i];
}

// ---- runtime input-dtype detection (1 = bf16, 0 = f32); proven: picks f32 here ----
__global__ void k_detect(const u16* __restrict__ enc, int* __restrict__ flag){
  __shared__ int cnt;
  if (threadIdx.x == 0) cnt = 0;
  __syncthreads();
  int c = 0;
  for (int j = threadIdx.x; j < 512; j += 256){
    u32 u = enc[j];
    u32 e = (u >> 7) & 0xFFu;
    c += (u == 0u || (e >= 100u && e <= 130u)) ? 1 : 0;
  }
  atomicAdd(&cnt, c);
  __syncthreads();
  if (threadIdx.x == 0) *flag = (cnt > 410) ? 1 : 0;
}

// ---- init: X = emb[idx], Hb = h1 (both f32 in ws) ----
__global__ void k_init(const int* __restrict__ idx, const void* __restrict__ emb,
                       const void* __restrict__ h1, float* __restrict__ X, float* __restrict__ Hb,
                       const int* __restrict__ flagp){
  int bf = *flagp;
  int t = blockIdx.x * 256 + threadIdx.x;   // B*H threads
  int b = t >> 10, h = t & (H - 1);
  X[t]  = ldf(emb, (size_t)idx[b] * H + h, bf);
  Hb[t] = ldf(h1, t, bf);
}

// ---- split-K GEMM: partial[b,n] = A[b, kbase:kbase+Kc] @ W[n, kbase:kbase+Kc]^T ----
// OUT 0: P[split] = partial      OUT 1: P[split] += partial      OUT 2: C = partial + bias (direct)
// Tile: 128 b x 64 n per block; grid = (N/64, splits); Kc = K/splits (multiple of 32).
template<int OUT>
__global__ __launch_bounds__(256)
void gemm_s(const float* __restrict__ A, const void* __restrict__ W, size_t wOff,
            const void* __restrict__ bias, float* __restrict__ P,
            int K, int Kc, int N, const int* __restrict__ flagp)
{
  const int bf = *flagp;
  __shared__ float As[32][132];   // [k][b], padded
  __shared__ float Wt[32][68];    // [k][n], padded (row stride 272B, 16B-aligned)
  const int t  = threadIdx.x;
  const int n0 = blockIdx.x * 64;
  const int kbase = blockIdx.y * Kc;
  const int sb = t >> 1,  sk = (t & 1) << 4;   // A staging: b, k-offset (16 k per thread)
  const int wn = t >> 2,  wk = (t & 3) << 3;   // W staging: n, k-offset (8 k per thread)
  const int bx = (t & 15) << 3;                // 8 b-rows per thread
  const int ny = (t >> 4) << 2;                // 4 n-cols per thread

  float acc[8][4];
  #pragma unroll
  for (int i = 0; i < 8; ++i)
    #pragma unroll
    for (int j = 0; j < 4; ++j) acc[i][j] = 0.f;

  for (int k0 = 0; k0 < Kc; k0 += 32){
    const int kb = kbase + k0;
    const float4* Ap = (const float4*)(A + (size_t)sb * K + kb + sk);
    float4 a0 = Ap[0], a1 = Ap[1], a2 = Ap[2], a3 = Ap[3];
    size_t we = wOff + (size_t)(n0 + wn) * K + kb + wk;
    float w0,w1,w2,w3,w4,w5,w6,w7;
    if (bf){
      uint4 wv = *(const uint4*)((const u16*)W + we);
      w0=b2f(wv.x); w1=b2f(wv.x>>16); w2=b2f(wv.y); w3=b2f(wv.y>>16);
      w4=b2f(wv.z); w5=b2f(wv.z>>16); w6=b2f(wv.w); w7=b2f(wv.w>>16);
    } else {
      const float* Wf = (const float*)W + we;
      float4 p = *(const float4*)Wf, q = *(const float4*)(Wf + 4);
      w0=p.x; w1=p.y; w2=p.z; w3=p.w; w4=q.x; w5=q.y; w6=q.z; w7=q.w;
    }

    As[sk+ 0][sb]=a0.x; As[sk+ 1][sb]=a0.y; As[sk+ 2][sb]=a0.z; As[sk+ 3][sb]=a0.w;
    As[sk+ 4][sb]=a1.x; As[sk+ 5][sb]=a1.y; As[sk+ 6][sb]=a1.z; As[sk+ 7][sb]=a1.w;
    As[sk+ 8][sb]=a2.x; As[sk+ 9][sb]=a2.y; As[sk+10][sb]=a2.z; As[sk+11][sb]=a2.w;
    As[sk+12][sb]=a3.x; As[sk+13][sb]=a3.y; As[sk+14][sb]=a3.z; As[sk+15][sb]=a3.w;
    Wt[wk+0][wn]=w0; Wt[wk+1][wn]=w1; Wt[wk+2][wn]=w2; Wt[wk+3][wn]=w3;
    Wt[wk+4][wn]=w4; Wt[wk+5][wn]=w5; Wt[wk+6][wn]=w6; Wt[wk+7][wn]=w7;
    __syncthreads();

    #pragma unroll
    for (int kk = 0; kk < 32; ++kk){
      float4 wv = *(const float4*)(&Wt[kk][ny]);
      float a[8];
      #pragma unroll
      for (int i = 0; i < 8; ++i) a[i] = As[kk][bx+i];
      #pragma unroll
      for (int i = 0; i < 8; ++i){
        acc[i][0] = fmaf(a[i], wv.x, acc[i][0]);
        acc[i][1] = fmaf(a[i], wv.y, acc[i][1]);
        acc[i][2] = fmaf(a[i], wv.z, acc[i][2]);
        acc[i][3] = fmaf(a[i], wv.w, acc[i][3]);
      }
    }
    __syncthreads();
  }

  float* Pp = P + (size_t)blockIdx.y * B * N;
  #pragma unroll
  for (int j = 0; j < 4; ++j){
    int n = n0 + ny + j;
    float bj = (OUT == 2 && bias) ? ldf(bias, n, bf) : 0.f;
    #pragma unroll
    for (int i = 0; i < 8; ++i){
      size_t o = (size_t)(bx + i) * N + n;
      if (OUT == 0)      Pp[o] = acc[i][j];
      else if (OUT == 1) Pp[o] += acc[i][j];
      else               P[o] = acc[i][j] + bj;    // direct: P is C, ignore split offset
    }
  }
}

// ---- epilogue over B*H: sum splits + bias, then activation ----
// ACT 0: C = s     ACT 1: C = tanh(s)     ACT 2: C = C * 2*sigmoid(s)   (mogrifier)
template<int ACT>
__global__ void ep_gen(const float* __restrict__ P, int S, const void* __restrict__ bias,
                       size_t bOff, float* __restrict__ C, const int* __restrict__ flagp){
  int bf = *flagp;
  int t = blockIdx.x * 256 + threadIdx.x;   // B*H
  int h = t & (H - 1);
  float s = 0.f;
  for (int i = 0; i < S; ++i) s += P[(size_t)i * B * H + t];
  s += ldf(bias, bOff + h, bf);
  if (ACT == 0)      C[t] = s;
  else if (ACT == 1) C[t] = tanhf(s);
  else               C[t] = C[t] * 2.f * sigm(s);
}

// ---- epilogue: sum gate splits + biases -> LSTM pointwise -> h ----
__global__ void ep_lstm(const float* __restrict__ P, int S, const void* __restrict__ bih,
                        const void* __restrict__ bhh, const void* __restrict__ cprev,
                        float* __restrict__ hout, float* __restrict__ hf,
                        const int* __restrict__ flagp){
  int bf = *flagp;
  int t = blockIdx.x * 256 + threadIdx.x;   // B*H
  int b = t >> 10, h = t & (H - 1);
  size_t base = (size_t)b * 4 * H;
  float gi=0.f, gf=0.f, gg=0.f, go=0.f;
  for (int s = 0; s < S; ++s){
    const float* q = P + (size_t)s * B * 4 * H + base;
    gi += q[h]; gf += q[H + h]; gg += q[2*H + h]; go += q[3*H + h];
  }
  gi += ldf(bih, h, bf)       + ldf(bhh, h, bf);
  gf += ldf(bih, H + h, bf)   + ldf(bhh, H + h, bf);
  gg += ldf(bih, 2*H + h, bf) + ldf(bhh, 2*H + h, bf);
  go += ldf(bih, 3*H + h, bf) + ldf(bhh, 3*H + h, bf);
  float c = cprev ? sigm(gf) * ldf(cprev, t, bf) : 0.f;
  c += sigm(gi) * tanhf(gg);
  float hv = sigm(go) * tanhf(c);
  hout[t] = hv;
  if (hf) hf[t] = hv;
}

// ---- layer-2 mogrifier collapse: X *= 8*sig(b0)*sig(b2)*sig(b4) ----
__global__ void k_scale2(float* __restrict__ X, const void* __restrict__ mb,
                         const int* __restrict__ flagp){
  int bf = *flagp;
  int t = blockIdx.x * 256 + threadIdx.x;   // B*H
  int h = t & (H - 1);
  float s = 8.f * sigm(ldf(mb, h, bf)) * sigm(ldf(mb, 2*H + h, bf)) * sigm(ldf(mb, 4*H + h, bf));
  X[t] *= s;
}

// ---- scores[b][s] = sum_h R[b][h]*enc[s][b][h]; one wave per (b,s) ----
__global__ __launch_bounds__(256)
void k_scores(const float* __restrict__ R, const void* __restrict__ enc, float* __restrict__ SC,
              const int* __restrict__ flagp){
  int bf = *flagp;
  int wid  = (blockIdx.x << 2) + (threadIdx.x >> 6);
  int lane = threadIdx.x & 63;
  int b = wid >> 9, s = wid & (SEQ - 1);
  size_t base = ((size_t)s * B + b) * H;
  const float* r = R + (size_t)b * H;
  float acc = 0.f;
  #pragma unroll
  for (int k0 = 0; k0 < H; k0 += 512){
    int h = k0 + lane * 8;
    float e0,e1,e2,e3,e4,e5,e6,e7;
    if (bf){
      uint4 u = *(const uint4*)((const u16*)enc + base + h);
      e0=b2f(u.x); e1=b2f(u.x>>16); e2=b2f(u.y); e3=b2f(u.y>>16);
      e4=b2f(u.z); e5=b2f(u.z>>16); e6=b2f(u.w); e7=b2f(u.w>>16);
    } else {
      const float* ef = (const float*)enc + base + h;
      float4 p = *(const float4*)ef, q = *(const float4*)(ef + 4);
      e0=p.x; e1=p.y; e2=p.z; e3=p.w; e4=q.x; e5=q.y; e6=q.z; e7=q.w;
    }
    float4 r0 = *(const float4*)(r + h);
    float4 r1 = *(const float4*)(r + h + 4);
    acc += e0*r0.x + e1*r0.y + e2*r0.z + e3*r0.w
         + e4*r1.x + e5*r1.y + e6*r1.z + e7*r1.w;
  }
  #pragma unroll
  for (int o = 32; o; o >>= 1) acc += __shfl_down(acc, o);
  if (lane == 0) SC[(size_t)b * SEQ + s] = acc;
}

// ---- softmax over S (in-place, f32), one block per b ----
__global__ __launch_bounds__(256)
void k_softmax_s(float* __restrict__ SC){
  int b = blockIdx.x, t = threadIdx.x;
  float* row = SC + (size_t)b * SEQ;
  float v0 = row[t], v1 = row[t + 256];
  __shared__ float rm[4], rs[4];
  int lane = t & 63, w = t >> 6;
  float m = fmaxf(v0, v1);
  #pragma unroll
  for (int o = 32; o; o >>= 1) m = fmaxf(m, __shfl_down(m, o));
  if (!lane) rm[w] = m;
  __syncthreads();
  float M = fmaxf(fmaxf(rm[0], rm[1]), fmaxf(rm[2], rm[3]));
  float e0 = expf(v0 - M), e1 = expf(v1 - M);
  float s = e0 + e1;
  #pragma unroll
  for (int o = 32; o; o >>= 1) s += __shfl_down(s, o);
  if (!lane) rs[w] = s;
  __syncthreads();
  float inv = 1.f / (rs[0] + rs[1] + rs[2] + rs[3]);
  row[t] = e0 * inv; row[t + 256] = e1 * inv;
}

// ---- context partials: CP[ch][b][h] = sum_{s in chunk} attn[b][s]*enc[s][b][h] ----
__global__ __launch_bounds__(256)
void k_context(const float* __restrict__ SC, const void* __restrict__ enc, float* __restrict__ CP,
               const int* __restrict__ flagp){
  int bf = *flagp;
  int b = blockIdx.x, ch = blockIdx.y, t = threadIdx.x;
  __shared__ float aw[128];
  if (t < 128) aw[t] = SC[(size_t)b * SEQ + ch * 128 + t];
  __syncthreads();
  int h0 = t << 2;
  float a0=0.f, a1=0.f, a2=0.f, a3=0.f;
  for (int ss = 0; ss < 128; ++ss){
    size_t off = ((size_t)(ch * 128 + ss) * B + b) * H + h0;
    float e0,e1,e2,e3;
    if (bf){
      uint2 u = *(const uint2*)((const u16*)enc + off);
      e0=b2f(u.x); e1=b2f(u.x>>16); e2=b2f(u.y); e3=b2f(u.y>>16);
    } else {
      float4 u = *(const float4*)((const float*)enc + off);
      e0=u.x; e1=u.y; e2=u.z; e3=u.w;
    }
    float wgt = aw[ss];
    a0 = fmaf(wgt, e0, a0);
    a1 = fmaf(wgt, e1, a1);
    a2 = fmaf(wgt, e2, a2);
    a3 = fmaf(wgt, e3, a3);
  }
  float4 o4 = {a0, a1, a2, a3};
  *(float4*)(CP + ((size_t)ch * B + b) * H + h0) = o4;
}

// ---- CAT[b][0:H]=R, CAT[b][H:2H]=sum of 4 context partials ----
__global__ void k_cat(const float* __restrict__ R, const float* __restrict__ CP, float* __restrict__ CAT){
  int t = blockIdx.x * 256 + threadIdx.x;  // B*2H
  int b = t >> 11, k = t & 2047;
  float v;
  if (k < H) v = R[(size_t)b * H + k];
  else {
    size_t o = (size_t)b * H + (k - H);
    v = CP[o] + CP[(size_t)B*H + o] + CP[2*(size_t)B*H + o] + CP[3*(size_t)B*H + o];
  }
  CAT[t] = v;
}

// ---- softmax over VOUT, f32 in-place in d_out, one block per b ----
__global__ __launch_bounds__(256)
void k_softmax_v(float* __restrict__ out){
  int b = blockIdx.x, t = threadIdx.x;
  float* row = out + (size_t)b * VOUT;
  __shared__ float rm[4], rs[4];
  int lane = t & 63, w = t >> 6;
  float m = -3.0e38f;
  for (int i = 4*t; i < VOUT; i += 1024){
    float4 v = *(const float4*)(row + i);
    m = fmaxf(m, fmaxf(fmaxf(v.x, v.y), fmaxf(v.z, v.w)));
  }
  #pragma unroll
  for (int o = 32; o; o >>= 1) m = fmaxf(m, __shfl_down(m, o));
  if (!lane) rm[w] = m;
  __syncthreads();
  float M = fmaxf(fmaxf(rm[0], rm[1]), fmaxf(rm[2], rm[3]));
  float s = 0.f;
  for (int i = 4*t; i < VOUT; i += 1024){
    float4 v = *(const float4*)(row + i);
    s += expf(v.x-M) + expf(v.y-M) + expf(v.z-M) + expf(v.w-M);
  }
  #pragma unroll
  for (int o = 32; o; o >>= 1) s += __shfl_down(s, o);
  if (!lane) rs[w] = s;
  __syncthreads();
  float inv = 1.f / (rs[0] + rs[1] + rs[2] + rs[3]);
  for (int i = 4*t; i < VOUT; i += 1024){
    float4 v = *(const float4*)(row + i);
    v.x = expf(v.x-M)*inv; v.y = expf(v.y-M)*inv;
    v.z = expf(v.z-M)*inv; v.w = expf(v.w-M)*inv;
    *(float4*)(row + i) = v;
  }
}

extern "C" void kernel_launch(void* const* d_in, const int* in_sizes, int n_in,
                              void* d_out, int out_size, void* d_ws, size_t ws_size,
                              hipStream_t stream){
  (void)in_sizes; (void)n_in; (void)out_size;
  const int* idx   = (const int*)d_in[0];
  const void* enc  = d_in[1];
  const void* h1   = d_in[2];
  const void* c1   = d_in[3];
  const void* emb  = d_in[4];
  const void* mog1W= d_in[5];
  const void* mog1b= d_in[6];
  const void* Wih1 = d_in[7];
  const void* Whh1 = d_in[8];
  const void* bih1 = d_in[9];
  const void* bhh1 = d_in[10];
  // d_in[11] mog2_W: dead (layer-2 mogrifier h stays 0)
  const void* mog2b= d_in[12];
  const void* Wih2 = d_in[13];
  // d_in[14] lstm2_Whh: dead (h=0)
  const void* bih2 = d_in[15];
  const void* bhh2 = d_in[16];
  const void* fcW  = d_in[17];
  const void* fcb  = d_in[18];
  const void* ccW  = d_in[19];
  const void* ccb  = d_in[20];
  const void* outW = d_in[21];
  const void* outb = d_in[22];

  float* X   = (float*)d_ws;        // B*H  (x / h1n / concat_out)
  float* Hb  = X  + B*H;            // B*H  (h)
  float* H2  = Hb + B*H;            // B*H  (h2)
  float* R   = H2 + B*H;            // B*H  (rnn_out)
  float* SC  = R  + B*H;            // B*SEQ (scores -> attn)
  float* CAT = SC + B*SEQ;          // B*2H
  int*  FLAG = (int*)(CAT + (size_t)B*2*H);
  float* P   = (float*)(FLAG + 64); // split-K partials (max S2*B*4H) / context partials

  size_t base_bytes = ((size_t)(6*B*H + B*SEQ) + 64) * 4;
  int S1 = 8, S2 = 4;               // splits: B*H-output gemms / gate gemms
  if (ws_size < base_bytes + (size_t)S2*B*4*H*4) { S1 = 4; S2 = 1; }

  float* out_f = (float*)d_out;               // [B, VOUT] probs
  float* hid_f = out_f + (size_t)B * VOUT;    // [1, B, H] hidden

  k_detect<<<1, 256, 0, stream>>>((const u16*)enc, FLAG);
  k_init<<<B*H/256, 256, 0, stream>>>(idx, emb, h1, X, Hb, FLAG);

  // layer-1 mogrifier: i even -> x = 2sig(h@W^T+b)*x ; i odd -> h = 2sig(x@W^T+b)*h
  for (int i = 0; i < 5; ++i){
    const float* a = (i & 1) ? X : Hb;
    float*       c = (i & 1) ? Hb : X;
    gemm_s<0><<<dim3(H/64, S1), 256, 0, stream>>>(a, mog1W, (size_t)i*H*H, nullptr, P,
                                                  H, H/S1, H, FLAG);
    ep_gen<2><<<B*H/256, 256, 0, stream>>>(P, S1, mog1b, (size_t)i*H, c, FLAG);
  }

  // layer-1 LSTM gates: P = X@Wih1^T ; P += Hb@Whh1^T ; epilogue -> h1n in X
  gemm_s<0><<<dim3(4*H/64, S2), 256, 0, stream>>>(X,  Wih1, 0, nullptr, P, H, H/S2, 4*H, FLAG);
  gemm_s<1><<<dim3(4*H/64, S2), 256, 0, stream>>>(Hb, Whh1, 0, nullptr, P, H, H/S2, 4*H, FLAG);
  ep_lstm<<<B*H/256, 256, 0, stream>>>(P, S2, bih1, bhh1, c1, X, nullptr, FLAG);

  // layer-2 mogrifier collapse + LSTM (h=c=0)
  k_scale2<<<B*H/256, 256, 0, stream>>>(X, mog2b, FLAG);
  gemm_s<0><<<dim3(4*H/64, S2), 256, 0, stream>>>(X, Wih2, 0, nullptr, P, H, H/S2, 4*H, FLAG);
  ep_lstm<<<B*H/256, 256, 0, stream>>>(P, S2, bih2, bhh2, nullptr, H2, hid_f, FLAG);

  // fc -> R
  gemm_s<0><<<dim3(H/64, S1), 256, 0, stream>>>(H2, fcW, 0, nullptr, P, H, H/S1, H, FLAG);
  ep_gen<0><<<B*H/256, 256, 0, stream>>>(P, S1, fcb, 0, R, FLAG);

  // attention
  k_scores<<<B*SEQ/4, 256, 0, stream>>>(R, enc, SC, FLAG);
  k_softmax_s<<<B, 256, 0, stream>>>(SC);
  k_context<<<dim3(B, 4), 256, 0, stream>>>(SC, enc, P, FLAG);   // context partials overlay P
  k_cat<<<B*2*H/256, 256, 0, stream>>>(R, P, CAT);

  // concat fc (K=2H) -> X ; out logits (direct) -> d_out ; softmax
  gemm_s<0><<<dim3(H/64, S1), 256, 0, stream>>>(CAT, ccW, 0, nullptr, P, 2*H, 2*H/S1, H, FLAG);
  ep_gen<1><<<B*H/256, 256, 0, stream>>>(P, S1, ccb, 0, X, FLAG);
  gemm_s<2><<<dim3(VOUT/64, 1), 256, 0, stream>>>(X, outW, 0, outb, out_f, H, H, VOUT, FLAG);
  k_softmax_v<<<B, 256, 0, stream>>>(out_f);
}

// Round 5
// 975.418 us; speedup vs baseline: 1.9556x; 1.0551x over previous
//
#include <hip/hip_runtime.h>
#include <math.h>

typedef unsigned short u16;
typedef unsigned int   u32;

#define B    128
#define H    1024
#define SEQ  512
#define VOUT 32000

using bf16x8 = __attribute__((ext_vector_type(8))) short;
using f32x4  = __attribute__((ext_vector_type(4))) float;

__device__ __forceinline__ float b2f(u32 u){ return __uint_as_float((u & 0xffffu) << 16); }
__device__ __forceinline__ float sigm(float x){ return 1.0f / (1.0f + expf(-x)); }
__device__ __forceinline__ u32 cvt2(float a, float b){   // pack bf16(a) lo | bf16(b) hi, RNE
  u32 ua = __float_as_uint(a); ua += 0x7fffu + ((ua >> 16) & 1u);
  u32 ub = __float_as_uint(b); ub += 0x7fffu + ((ub >> 16) & 1u);
  return (ua >> 16) | (ub & 0xffff0000u);
}

// generic element load: bf=1 -> data is bf16 (u16); bf=0 -> data is f32
__device__ __forceinline__ float ldf(const void* p, size_t i, int bf){
  return bf ? b2f(((const u16*)p)[i]) : ((const float*)p)[i];
}

// ---- runtime input-dtype detection (1 = bf16, 0 = f32); proven: picks f32 here ----
__global__ void k_detect(const u16* __restrict__ enc, int* __restrict__ flag){
  __shared__ int cnt;
  if (threadIdx.x == 0) cnt = 0;
  __syncthreads();
  int c = 0;
  for (int j = threadIdx.x; j < 512; j += 256){
    u32 u = enc[j];
    u32 e = (u >> 7) & 0xFFu;
    c += (u == 0u || (e >= 100u && e <= 130u)) ? 1 : 0;
  }
  atomicAdd(&cnt, c);
  __syncthreads();
  if (threadIdx.x == 0) *flag = (cnt > 410) ? 1 : 0;
}

// ---- init: X = emb[idx], Hb = h1 (both f32 in ws) ----
__global__ void k_init(const int* __restrict__ idx, const void* __restrict__ emb,
                       const void* __restrict__ h1, float* __restrict__ X, float* __restrict__ Hb,
                       const int* __restrict__ flagp){
  int bf = *flagp;
  int t = blockIdx.x * 256 + threadIdx.x;   // B*H threads
  int b = t >> 10, h = t & (H - 1);
  X[t]  = ldf(emb, (size_t)idx[b] * H + h, bf);
  Hb[t] = ldf(h1, t, bf);
}

// ---- split-K GEMM: partial[b,n] = A[b, kbase:+Kc] @ W[n, kbase:+Kc]^T ----
// OUT 0: P[split] = partial      OUT 1: P[split] += partial
template<int OUT>
__global__ __launch_bounds__(256)
void gemm_s(const float* __restrict__ A, const void* __restrict__ W, size_t wOff,
            float* __restrict__ P, int K, int Kc, int N, const int* __restrict__ flagp)
{
  const int bf = *flagp;
  __shared__ float As[32][132];   // [k][b], padded
  __shared__ float Wt[32][68];    // [k][n], padded
  const int t  = threadIdx.x;
  const int n0 = blockIdx.x * 64;
  const int kbase = blockIdx.y * Kc;
  const int sb = t >> 1,  sk = (t & 1) << 4;
  const int wn = t >> 2,  wk = (t & 3) << 3;
  const int bx = (t & 15) << 3;
  const int ny = (t >> 4) << 2;

  float acc[8][4];
  #pragma unroll
  for (int i = 0; i < 8; ++i)
    #pragma unroll
    for (int j = 0; j < 4; ++j) acc[i][j] = 0.f;

  for (int k0 = 0; k0 < Kc; k0 += 32){
    const int kb = kbase + k0;
    const float4* Ap = (const float4*)(A + (size_t)sb * K + kb + sk);
    float4 a0 = Ap[0], a1 = Ap[1], a2 = Ap[2], a3 = Ap[3];
    size_t we = wOff + (size_t)(n0 + wn) * K + kb + wk;
    float w0,w1,w2,w3,w4,w5,w6,w7;
    if (bf){
      uint4 wv = *(const uint4*)((const u16*)W + we);
      w0=b2f(wv.x); w1=b2f(wv.x>>16); w2=b2f(wv.y); w3=b2f(wv.y>>16);
      w4=b2f(wv.z); w5=b2f(wv.z>>16); w6=b2f(wv.w); w7=b2f(wv.w>>16);
    } else {
      const float* Wf = (const float*)W + we;
      float4 p = *(const float4*)Wf, q = *(const float4*)(Wf + 4);
      w0=p.x; w1=p.y; w2=p.z; w3=p.w; w4=q.x; w5=q.y; w6=q.z; w7=q.w;
    }

    As[sk+ 0][sb]=a0.x; As[sk+ 1][sb]=a0.y; As[sk+ 2][sb]=a0.z; As[sk+ 3][sb]=a0.w;
    As[sk+ 4][sb]=a1.x; As[sk+ 5][sb]=a1.y; As[sk+ 6][sb]=a1.z; As[sk+ 7][sb]=a1.w;
    As[sk+ 8][sb]=a2.x; As[sk+ 9][sb]=a2.y; As[sk+10][sb]=a2.z; As[sk+11][sb]=a2.w;
    As[sk+12][sb]=a3.x; As[sk+13][sb]=a3.y; As[sk+14][sb]=a3.z; As[sk+15][sb]=a3.w;
    Wt[wk+0][wn]=w0; Wt[wk+1][wn]=w1; Wt[wk+2][wn]=w2; Wt[wk+3][wn]=w3;
    Wt[wk+4][wn]=w4; Wt[wk+5][wn]=w5; Wt[wk+6][wn]=w6; Wt[wk+7][wn]=w7;
    __syncthreads();

    #pragma unroll
    for (int kk = 0; kk < 32; ++kk){
      float4 wv = *(const float4*)(&Wt[kk][ny]);
      float a[8];
      #pragma unroll
      for (int i = 0; i < 8; ++i) a[i] = As[kk][bx+i];
      #pragma unroll
      for (int i = 0; i < 8; ++i){
        acc[i][0] = fmaf(a[i], wv.x, acc[i][0]);
        acc[i][1] = fmaf(a[i], wv.y, acc[i][1]);
        acc[i][2] = fmaf(a[i], wv.z, acc[i][2]);
        acc[i][3] = fmaf(a[i], wv.w, acc[i][3]);
      }
    }
    __syncthreads();
  }

  float* Pp = P + (size_t)blockIdx.y * B * N;
  #pragma unroll
  for (int j = 0; j < 4; ++j){
    int n = n0 + ny + j;
    #pragma unroll
    for (int i = 0; i < 8; ++i){
      size_t o = (size_t)(bx + i) * N + n;
      if (OUT == 0) Pp[o] = acc[i][j];
      else          Pp[o] += acc[i][j];
    }
  }
}

// ---- epilogue over B*H: sum splits + bias, activation, strided store ----
// ACT 0: C = s     ACT 1: C = tanh(s)     ACT 2: C = C * 2*sigmoid(s)
template<int ACT>
__global__ void ep_gen(const float* __restrict__ P, int S, const void* __restrict__ bias,
                       size_t bOff, float* __restrict__ C, int ostr,
                       const int* __restrict__ flagp){
  int bf = *flagp;
  int t = blockIdx.x * 256 + threadIdx.x;   // B*H
  int b = t >> 10, h = t & (H - 1);
  float s = 0.f;
  for (int i = 0; i < S; ++i) s += P[(size_t)i * B * H + t];
  s += ldf(bias, bOff + h, bf);
  size_t o = (size_t)b * ostr + h;
  if (ACT == 0)      C[o] = s;
  else if (ACT == 1) C[o] = tanhf(s);
  else               C[o] = C[o] * 2.f * sigm(s);
}

// ---- epilogue: sum gate splits + biases -> LSTM pointwise -> h (opt. mog2 scale) ----
__global__ void ep_lstm(const float* __restrict__ P, int S, const void* __restrict__ bih,
                        const void* __restrict__ bhh, const void* __restrict__ cprev,
                        float* __restrict__ hout, float* __restrict__ hf,
                        const void* __restrict__ mog2b, const int* __restrict__ flagp){
  int bf = *flagp;
  int t = blockIdx.x * 256 + threadIdx.x;   // B*H
  int b = t >> 10, h = t & (H - 1);
  size_t base = (size_t)b * 4 * H;
  float gi=0.f, gf=0.f, gg=0.f, go=0.f;
  for (int s = 0; s < S; ++s){
    const float* q = P + (size_t)s * B * 4 * H + base;
    gi += q[h]; gf += q[H + h]; gg += q[2*H + h]; go += q[3*H + h];
  }
  gi += ldf(bih, h, bf)       + ldf(bhh, h, bf);
  gf += ldf(bih, H + h, bf)   + ldf(bhh, H + h, bf);
  gg += ldf(bih, 2*H + h, bf) + ldf(bhh, 2*H + h, bf);
  go += ldf(bih, 3*H + h, bf) + ldf(bhh, 3*H + h, bf);
  float c = cprev ? sigm(gf) * ldf(cprev, t, bf) : 0.f;
  c += sigm(gi) * tanhf(gg);
  float hv = sigm(go) * tanhf(c);
  if (hf) hf[t] = hv;                 // raw hidden to d_out (layer 2)
  if (mog2b){                         // fold layer-2 mogrifier collapse into the store
    hv *= 8.f * sigm(ldf(mog2b, h, bf)) * sigm(ldf(mog2b, 2*H + h, bf))
              * sigm(ldf(mog2b, 4*H + h, bf));
  }
  hout[t] = hv;
}

// ---- scores[b][s] = sum_h R[b][h]*enc[s][b][h]; R strided in CAT; one wave/(b,s) ----
__global__ __launch_bounds__(256)
void k_scores(const float* __restrict__ CAT, const void* __restrict__ enc, float* __restrict__ SC,
              const int* __restrict__ flagp){
  int bf = *flagp;
  int wid  = (blockIdx.x << 2) + (threadIdx.x >> 6);
  int lane = threadIdx.x & 63;
  int b = wid >> 9, s = wid & (SEQ - 1);
  size_t base = ((size_t)s * B + b) * H;
  const float* r = CAT + (size_t)b * 2 * H;
  float acc = 0.f;
  #pragma unroll
  for (int k0 = 0; k0 < H; k0 += 512){
    int h = k0 + lane * 8;
    float e0,e1,e2,e3,e4,e5,e6,e7;
    if (bf){
      uint4 u = *(const uint4*)((const u16*)enc + base + h);
      e0=b2f(u.x); e1=b2f(u.x>>16); e2=b2f(u.y); e3=b2f(u.y>>16);
      e4=b2f(u.z); e5=b2f(u.z>>16); e6=b2f(u.w); e7=b2f(u.w>>16);
    } else {
      const float* ef = (const float*)enc + base + h;
      float4 p = *(const float4*)ef, q = *(const float4*)(ef + 4);
      e0=p.x; e1=p.y; e2=p.z; e3=p.w; e4=q.x; e5=q.y; e6=q.z; e7=q.w;
    }
    float4 r0 = *(const float4*)(r + h);
    float4 r1 = *(const float4*)(r + h + 4);
    acc += e0*r0.x + e1*r0.y + e2*r0.z + e3*r0.w
         + e4*r1.x + e5*r1.y + e6*r1.z + e7*r1.w;
  }
  #pragma unroll
  for (int o = 32; o; o >>= 1) acc += __shfl_down(acc, o);
  if (lane == 0) SC[(size_t)b * SEQ + s] = acc;
}

// ---- softmax over S (in-place, f32), one block per b ----
__global__ __launch_bounds__(256)
void k_softmax_s(float* __restrict__ SC){
  int b = blockIdx.x, t = threadIdx.x;
  float* row = SC + (size_t)b * SEQ;
  float v0 = row[t], v1 = row[t + 256];
  __shared__ float rm[4], rs[4];
  int lane = t & 63, w = t >> 6;
  float m = fmaxf(v0, v1);
  #pragma unroll
  for (int o = 32; o; o >>= 1) m = fmaxf(m, __shfl_down(m, o));
  if (!lane) rm[w] = m;
  __syncthreads();
  float M = fmaxf(fmaxf(rm[0], rm[1]), fmaxf(rm[2], rm[3]));
  float e0 = expf(v0 - M), e1 = expf(v1 - M);
  float s = e0 + e1;
  #pragma unroll
  for (int o = 32; o; o >>= 1) s += __shfl_down(s, o);
  if (!lane) rs[w] = s;
  __syncthreads();
  float inv = 1.f / (rs[0] + rs[1] + rs[2] + rs[3]);
  row[t] = e0 * inv; row[t + 256] = e1 * inv;
}

// ---- context directly into CAT[b][H + h]: one block per b, full S sweep ----
__global__ __launch_bounds__(256)
void k_context(const float* __restrict__ SC, const void* __restrict__ enc, float* __restrict__ CAT,
               const int* __restrict__ flagp){
  int bf = *flagp;
  int b = blockIdx.x, t = threadIdx.x;
  __shared__ float aw[SEQ];
  aw[t] = SC[(size_t)b * SEQ + t];
  aw[t + 256] = SC[(size_t)b * SEQ + t + 256];
  __syncthreads();
  int h0 = t << 2;
  float a0=0.f, a1=0.f, a2=0.f, a3=0.f;
  for (int ss = 0; ss < SEQ; ++ss){
    size_t off = ((size_t)ss * B + b) * H + h0;
    float e0,e1,e2,e3;
    if (bf){
      uint2 u = *(const uint2*)((const u16*)enc + off);
      e0=b2f(u.x); e1=b2f(u.x>>16); e2=b2f(u.y); e3=b2f(u.y>>16);
    } else {
      float4 u = *(const float4*)((const float*)enc + off);
      e0=u.x; e1=u.y; e2=u.z; e3=u.w;
    }
    float wgt = aw[ss];
    a0 = fmaf(wgt, e0, a0);
    a1 = fmaf(wgt, e1, a1);
    a2 = fmaf(wgt, e2, a2);
    a3 = fmaf(wgt, e3, a3);
  }
  float4 o4 = {a0, a1, a2, a3};
  *(float4*)(CAT + (size_t)b * 2 * H + H + h0) = o4;
}

// ---- X (f32, B*H) -> Xb (bf16) ----
__global__ void k_cvtA(const float* __restrict__ X, u16* __restrict__ Xb){
  int t = blockIdx.x * 256 + threadIdx.x;   // B*H/8 threads
  const float4* p = (const float4*)(X + t * 8);
  float4 f0 = p[0], f1 = p[1];
  uint4 o;
  o.x = cvt2(f0.x, f0.y); o.y = cvt2(f0.z, f0.w);
  o.z = cvt2(f1.x, f1.y); o.w = cvt2(f1.z, f1.w);
  *(uint4*)(Xb + t * 8) = o;
}

// ---- out-GEMM via bf16 MFMA: C[128, VOUT] = Xb @ W^T + bias (W f32/bf16 in HBM) ----
__global__ __launch_bounds__(256)
void gemm_out_mfma(const u16* __restrict__ Xb, const void* __restrict__ W,
                   const void* __restrict__ bias, float* __restrict__ Cg,
                   const int* __restrict__ flagp)
{
  const int bf = *flagp;
  __shared__ u16 Ws[64][72];          // [n][k], 144-B row stride (16B-aligned, 2-way banks)
  const int t = threadIdx.x;
  const int n0 = blockIdx.x * 64;
  const int wave = t >> 6, lane = t & 63;
  const int m0 = wave * 32;
  const int lm = lane & 15, quad = lane >> 4;
  const int sn = t >> 2, sk = (t & 3) * 16;   // staging: 64 n-rows x 4 thr x 16 k

  f32x4 acc[2][4];
  #pragma unroll
  for (int i = 0; i < 2; ++i)
    #pragma unroll
    for (int j = 0; j < 4; ++j) acc[i][j] = (f32x4){0.f, 0.f, 0.f, 0.f};

  for (int k0 = 0; k0 < H; k0 += 64){
    if (bf){
      const u16* wp = (const u16*)W + (size_t)(n0 + sn) * H + k0 + sk;
      *(uint4*)(&Ws[sn][sk])     = *(const uint4*)wp;
      *(uint4*)(&Ws[sn][sk + 8]) = *(const uint4*)(wp + 8);
    } else {
      const float* wp = (const float*)W + (size_t)(n0 + sn) * H + k0 + sk;
      float4 f0 = *(const float4*)wp,     f1 = *(const float4*)(wp + 4);
      float4 f2 = *(const float4*)(wp+8), f3 = *(const float4*)(wp + 12);
      uint4 o0, o1;
      o0.x = cvt2(f0.x, f0.y); o0.y = cvt2(f0.z, f0.w);
      o0.z = cvt2(f1.x, f1.y); o0.w = cvt2(f1.z, f1.w);
      o1.x = cvt2(f2.x, f2.y); o1.y = cvt2(f2.z, f2.w);
      o1.z = cvt2(f3.x, f3.y); o1.w = cvt2(f3.z, f3.w);
      *(uint4*)(&Ws[sn][sk])     = o0;
      *(uint4*)(&Ws[sn][sk + 8]) = o1;
    }
    __syncthreads();
    #pragma unroll
    for (int ks = 0; ks < 64; ks += 32){
      bf16x8 a0 = *(const bf16x8*)(Xb + (size_t)(m0 + lm) * H + k0 + ks + quad * 8);
      bf16x8 a1 = *(const bf16x8*)(Xb + (size_t)(m0 + 16 + lm) * H + k0 + ks + quad * 8);
      #pragma unroll
      for (int nt = 0; nt < 4; ++nt){
        bf16x8 bfr = *(const bf16x8*)(&Ws[nt * 16 + lm][ks + quad * 8]);
        acc[0][nt] = __builtin_amdgcn_mfma_f32_16x16x32_bf16(a0, bfr, acc[0][nt], 0, 0, 0);
        acc[1][nt] = __builtin_amdgcn_mfma_f32_16x16x32_bf16(a1, bfr, acc[1][nt], 0, 0, 0);
      }
    }
    __syncthreads();
  }

  #pragma unroll
  for (int nt = 0; nt < 4; ++nt){
    int n = n0 + nt * 16 + lm;
    float bj = ldf(bias, n, bf);
    #pragma unroll
    for (int mt = 0; mt < 2; ++mt)
      #pragma unroll
      for (int r = 0; r < 4; ++r){
        int m = m0 + mt * 16 + quad * 4 + r;
        Cg[(size_t)m * VOUT + n] = acc[mt][nt][r] + bj;
      }
  }
}

// ---- softmax over VOUT, f32 in-place in d_out, one block per b ----
__global__ __launch_bounds__(256)
void k_softmax_v(float* __restrict__ out){
  int b = blockIdx.x, t = threadIdx.x;
  float* row = out + (size_t)b * VOUT;
  __shared__ float rm[4], rs[4];
  int lane = t & 63, w = t >> 6;
  float m = -3.0e38f;
  for (int i = 4*t; i < VOUT; i += 1024){
    float4 v = *(const float4*)(row + i);
    m = fmaxf(m, fmaxf(fmaxf(v.x, v.y), fmaxf(v.z, v.w)));
  }
  #pragma unroll
  for (int o = 32; o; o >>= 1) m = fmaxf(m, __shfl_down(m, o));
  if (!lane) rm[w] = m;
  __syncthreads();
  float M = fmaxf(fmaxf(rm[0], rm[1]), fmaxf(rm[2], rm[3]));
  float s = 0.f;
  for (int i = 4*t; i < VOUT; i += 1024){
    float4 v = *(const float4*)(row + i);
    s += expf(v.x-M) + expf(v.y-M) + expf(v.z-M) + expf(v.w-M);
  }
  #pragma unroll
  for (int o = 32; o; o >>= 1) s += __shfl_down(s, o);
  if (!lane) rs[w] = s;
  __syncthreads();
  float inv = 1.f / (rs[0] + rs[1] + rs[2] + rs[3]);
  for (int i = 4*t; i < VOUT; i += 1024){
    float4 v = *(const float4*)(row + i);
    v.x = expf(v.x-M)*inv; v.y = expf(v.y-M)*inv;
    v.z = expf(v.z-M)*inv; v.w = expf(v.w-M)*inv;
    *(float4*)(row + i) = v;
  }
}

extern "C" void kernel_launch(void* const* d_in, const int* in_sizes, int n_in,
                              void* d_out, int out_size, void* d_ws, size_t ws_size,
                              hipStream_t stream){
  (void)in_sizes; (void)n_in; (void)out_size;
  const int* idx   = (const int*)d_in[0];
  const void* enc  = d_in[1];
  const void* h1   = d_in[2];
  const void* c1   = d_in[3];
  const void* emb  = d_in[4];
  const void* mog1W= d_in[5];
  const void* mog1b= d_in[6];
  const void* Wih1 = d_in[7];
  const void* Whh1 = d_in[8];
  const void* bih1 = d_in[9];
  const void* bhh1 = d_in[10];
  // d_in[11] mog2_W: dead (layer-2 mogrifier h stays 0)
  const void* mog2b= d_in[12];
  const void* Wih2 = d_in[13];
  // d_in[14] lstm2_Whh: dead (h=0)
  const void* bih2 = d_in[15];
  const void* bhh2 = d_in[16];
  const void* fcW  = d_in[17];
  const void* fcb  = d_in[18];
  const void* ccW  = d_in[19];
  const void* ccb  = d_in[20];
  const void* outW = d_in[21];
  const void* outb = d_in[22];

  float* X    = (float*)d_ws;         // B*H  (x / h1n-scaled / concat_out)
  float* Hb   = X   + B*H;            // B*H  (h)
  float* H2   = Hb  + B*H;            // B*H  (h2)
  float* CAT  = H2  + B*H;            // B*2H (rnn_out | context)
  float* SC   = CAT + (size_t)B*2*H;  // B*SEQ (scores -> attn)
  int*  FLAG  = (int*)(SC + B*SEQ);   // 64 ints
  u16*  Xb    = (u16*)(FLAG + 64);    // B*H bf16
  float* P    = (float*)(Xb + B*H);   // split-K partials (S2*B*4H f32 max)

  size_t need = ((size_t)(5*B*H + B*SEQ) + 64) * 4 + (size_t)B*H*2 + (size_t)4*B*4*H*4;
  int S1 = 8, S2 = 4;
  if (ws_size < need) { S1 = 4; S2 = 1; }

  float* out_f = (float*)d_out;               // [B, VOUT] probs
  float* hid_f = out_f + (size_t)B * VOUT;    // [1, B, H] hidden

  k_detect<<<1, 256, 0, stream>>>((const u16*)enc, FLAG);
  k_init<<<B*H/256, 256, 0, stream>>>(idx, emb, h1, X, Hb, FLAG);

  // layer-1 mogrifier: i even -> x = 2sig(h@W^T+b)*x ; i odd -> h = 2sig(x@W^T+b)*h
  for (int i = 0; i < 5; ++i){
    const float* a = (i & 1) ? X : Hb;
    float*       c = (i & 1) ? Hb : X;
    gemm_s<0><<<dim3(H/64, S1), 256, 0, stream>>>(a, mog1W, (size_t)i*H*H, P, H, H/S1, H, FLAG);
    ep_gen<2><<<B*H/256, 256, 0, stream>>>(P, S1, mog1b, (size_t)i*H, c, H, FLAG);
  }

  // layer-1 LSTM gates -> h1n (scaled by layer-2 mogrifier collapse) into X
  gemm_s<0><<<dim3(4*H/64, S2), 256, 0, stream>>>(X,  Wih1, 0, P, H, H/S2, 4*H, FLAG);
  gemm_s<1><<<dim3(4*H/64, S2), 256, 0, stream>>>(Hb, Whh1, 0, P, H, H/S2, 4*H, FLAG);
  ep_lstm<<<B*H/256, 256, 0, stream>>>(P, S2, bih1, bhh1, c1, X, nullptr, mog2b, FLAG);

  // layer-2 LSTM (h=c=0) -> H2 + f32 hidden out
  gemm_s<0><<<dim3(4*H/64, S2), 256, 0, stream>>>(X, Wih2, 0, P, H, H/S2, 4*H, FLAG);
  ep_lstm<<<B*H/256, 256, 0, stream>>>(P, S2, bih2, bhh2, nullptr, H2, hid_f, nullptr, FLAG);

  // fc -> rnn_out straight into CAT[:, 0:H]
  gemm_s<0><<<dim3(H/64, S1), 256, 0, stream>>>(H2, fcW, 0, P, H, H/S1, H, FLAG);
  ep_gen<0><<<B*H/256, 256, 0, stream>>>(P, S1, fcb, 0, CAT, 2*H, FLAG);

  // attention: scores -> softmax -> context into CAT[:, H:2H]
  k_scores<<<B*SEQ/4, 256, 0, stream>>>(CAT, enc, SC, FLAG);
  k_softmax_s<<<B, 256, 0, stream>>>(SC);
  k_context<<<B, 256, 0, stream>>>(SC, enc, CAT, FLAG);

  // concat fc (K=2H) -> X ; MFMA out logits -> d_out ; vocab softmax
  gemm_s<0><<<dim3(H/64, S1), 256, 0, stream>>>(CAT, ccW, 0, P, 2*H, 2*H/S1, H, FLAG);
  ep_gen<1><<<B*H/256, 256, 0, stream>>>(P, S1, ccb, 0, X, H, FLAG);
  k_cvtA<<<B*H/(256*8), 256, 0, stream>>>(X, Xb);
  gemm_out_mfma<<<VOUT/64, 256, 0, stream>>>(Xb, outW, outb, out_f, FLAG);
  k_softmax_v<<<B, 256, 0, stream>>>(out_f);
}